// Round 10
// baseline (265.924 us; speedup 1.0000x reference)
//
#include <hip/hip_runtime.h>
#include <hip/hip_bf16.h>

// Problem constants
#define BB 4
#define SS 2048
#define DD 1024
#define HH 16
#define HDD 64

typedef __attribute__((ext_vector_type(8))) short bf16x8;
typedef __attribute__((ext_vector_type(8))) unsigned short u16x8;
typedef __attribute__((ext_vector_type(4))) float f32x4;
typedef __attribute__((ext_vector_type(4))) unsigned int u32x4;

#define GLD_LDS16(g, l) \
    __builtin_amdgcn_global_load_lds((const __attribute__((address_space(1))) void*)(g), \
                                     (__attribute__((address_space(3))) void*)(l), 16, 0, 0)

__device__ __forceinline__ unsigned short f32_to_bf16(float f) {
    unsigned int u = __float_as_uint(f);
    u += 0x7fffu + ((u >> 16) & 1u);   // RTNE
    return (unsigned short)(u >> 16);
}

__device__ __forceinline__ unsigned int cvt_pk_bf16(float lo, float hi) {
    unsigned int r;
    asm("v_cvt_pk_bf16_f32 %0, %1, %2" : "=v"(r) : "v"(lo), "v"(hi));
    return r;
}

__device__ __forceinline__ float fmax3(float a, float b, float c) {
    return fmaxf(fmaxf(a, b), c);   // fuses to v_max3_f32
}

// ---------------------------------------------------------------------------
// fp32 -> bf16 convert (vectorized, grid-stride)
// ---------------------------------------------------------------------------
__global__ __launch_bounds__(256) void convert_f32_bf16(
    const float* __restrict__ in, unsigned short* __restrict__ out, int n4) {
    int stride = gridDim.x * blockDim.x;
    for (int i = blockIdx.x * blockDim.x + threadIdx.x; i < n4; i += stride) {
        float4 v = ((const float4*)in)[i];
        ushort4 o;
        o.x = f32_to_bf16(v.x); o.y = f32_to_bf16(v.y);
        o.z = f32_to_bf16(v.z); o.w = f32_to_bf16(v.w);
        ((ushort4*)out)[i] = o;
    }
}

// ---------------------------------------------------------------------------
// Pack Wq/Wk/Wv [H][D][HD] fp32 -> WT [3*D][D] bf16 (B^T layout)
// ---------------------------------------------------------------------------
__global__ __launch_bounds__(256) void pack_wqkv(
    const float* __restrict__ Wq, const float* __restrict__ Wk,
    const float* __restrict__ Wv, unsigned short* __restrict__ WT) {
    int bid = blockIdx.x;
    int w = bid >> 8, h = (bid >> 4) & 15, db = bid & 15;
    const float* src = (w == 0) ? Wq : ((w == 1) ? Wk : Wv);
    __shared__ float tile[64][68];
    int t = threadIdx.x;
    for (int p = t; p < 1024; p += 256) {
        int row = p >> 4, c4 = p & 15;
        float4 v = *(const float4*)(src + ((size_t)(h * 1024 + db * 64 + row)) * 64 + c4 * 4);
        tile[row][c4 * 4 + 0] = v.x; tile[row][c4 * 4 + 1] = v.y;
        tile[row][c4 * 4 + 2] = v.z; tile[row][c4 * 4 + 3] = v.w;
    }
    __syncthreads();
    size_t wbase = (size_t)w * 1024 * 1024;
    for (int p = t; p < 512; p += 256) {
        int e = p >> 3, c = p & 7;
        u16x8 pk;
#pragma unroll
        for (int j = 0; j < 8; ++j) pk[j] = f32_to_bf16(tile[c * 8 + j][e]);
        *(u16x8*)(WT + wbase + (size_t)(h * 64 + e) * 1024 + db * 64 + c * 8) = pk;
    }
}

// ---------------------------------------------------------------------------
// 128x128 tile bf16 GEMM, BK=64, 4 waves, global_load_lds + XOR-swizzled LDS.
// XCD-aware bijective block swizzle (requires gridDim.x % 8 == 0).
// EPI 0: scatter C (bf16) into Q/K/V [B,H,S,HD]; Q pre-scaled by 0.125*log2e.
// EPI 1: C fp32 [M][1024].
// ---------------------------------------------------------------------------
template <int EPI>
__global__ __launch_bounds__(256) void gemm128(
    const unsigned short* __restrict__ A, const unsigned short* __restrict__ Bm,
    void* __restrict__ C0, void* __restrict__ C1, void* __restrict__ C2, int NBt) {
    __shared__ unsigned short As[128 * 64];
    __shared__ unsigned short Bs[128 * 64];
    // XCD swizzle: XCD x (bid%8) gets a contiguous chunk of tile space
    int cpx = gridDim.x >> 3;
    int bid = (blockIdx.x & 7) * cpx + (blockIdx.x >> 3);
    int mb = bid / NBt, nb = bid % NBt;
    int tid = threadIdx.x;
    int lane = tid & 63, wid = tid >> 6;
    int wm = wid >> 1, wn = wid & 1;
    int g = lane >> 4, lr = lane & 15;
    int srow = lane >> 3, sch = lane & 7;
    int scol = (sch ^ srow) * 8;
    const int M0 = mb * 128, N0 = nb * 128;

    f32x4 acc[4][4] = {};

    for (int kt = 0; kt < 16; ++kt) {
        __syncthreads();
#pragma unroll
        for (int i = 0; i < 4; ++i) {
            int c = wid * 4 + i;
            int row = c * 8 + srow;
            GLD_LDS16(A + (size_t)(M0 + row) * 1024 + kt * 64 + scol, As + c * 512);
            GLD_LDS16(Bm + (size_t)(N0 + row) * 1024 + kt * 64 + scol, Bs + c * 512);
        }
        __syncthreads();
#pragma unroll
        for (int kk = 0; kk < 2; ++kk) {
            bf16x8 af[4], bfr[4];
#pragma unroll
            for (int i = 0; i < 4; ++i) {
                int row = wm * 64 + i * 16 + lr;
                int ch = (kk * 4 + g) ^ (row & 7);
                af[i] = *(const bf16x8*)(As + row * 64 + ch * 8);
                int rowb = wn * 64 + i * 16 + lr;
                int chb = (kk * 4 + g) ^ (rowb & 7);
                bfr[i] = *(const bf16x8*)(Bs + rowb * 64 + chb * 8);
            }
            __builtin_amdgcn_s_setprio(1);
#pragma unroll
            for (int i = 0; i < 4; ++i)
#pragma unroll
                for (int j = 0; j < 4; ++j)
                    acc[i][j] = __builtin_amdgcn_mfma_f32_16x16x32_bf16(af[i], bfr[j], acc[i][j], 0, 0, 0);
            __builtin_amdgcn_s_setprio(0);
        }
    }

    if constexpr (EPI == 0) {
        unsigned short* Qo = (unsigned short*)C0;
        unsigned short* Ko = (unsigned short*)C1;
        unsigned short* Vo = (unsigned short*)C2;
        const float QSCALE = 0.125f * 1.4426950408889634f;  // scale * log2(e)
#pragma unroll
        for (int i = 0; i < 4; ++i)
#pragma unroll
            for (int j = 0; j < 4; ++j)
#pragma unroll
                for (int r = 0; r < 4; ++r) {
                    int m = M0 + wm * 64 + i * 16 + g * 4 + r;
                    int n = N0 + wn * 64 + j * 16 + lr;
                    int b = m >> 11, s = m & 2047;
                    int w = n >> 10, h = (n >> 6) & 15, e = n & 63;
                    unsigned short* dst = (w == 0) ? Qo : ((w == 1) ? Ko : Vo);
                    float scl = (w == 0) ? QSCALE : 1.0f;
                    dst[((size_t)(b * HH + h) * SS + s) * HDD + e] = f32_to_bf16(acc[i][j][r] * scl);
                }
    } else {
        float* Co = (float*)C0;
#pragma unroll
        for (int i = 0; i < 4; ++i)
#pragma unroll
            for (int j = 0; j < 4; ++j)
#pragma unroll
                for (int r = 0; r < 4; ++r) {
                    int m = M0 + wm * 64 + i * 16 + g * 4 + r;
                    int n = N0 + wn * 64 + j * 16 + lr;
                    Co[(size_t)m * 1024 + n] = acc[i][j][r];
                }
    }
}

// ---------------------------------------------------------------------------
// V [B,H,S,HD] -> VT [B,H,HD,S]  (LDS tile transpose)
// ---------------------------------------------------------------------------
__global__ __launch_bounds__(256) void transpose_v(
    const unsigned short* __restrict__ V, unsigned short* __restrict__ VT) {
    int bh = blockIdx.x >> 5, sb = blockIdx.x & 31;
    __shared__ unsigned short tile[64][72];
    const unsigned short* src = V + ((size_t)bh * SS + sb * 64) * HDD;
    int t = threadIdx.x;
    for (int p = t; p < 512; p += 256) {
        int row = p >> 3, c = p & 7;
        *(u16x8*)&tile[row][c * 8] = *(const u16x8*)(src + row * 64 + c * 8);
    }
    __syncthreads();
    unsigned short* dst = VT + (size_t)bh * HDD * SS + sb * 64;
    for (int p = t; p < 512; p += 256) {
        int e = p >> 3, c = p & 7;
        u16x8 pk;
#pragma unroll
        for (int j = 0; j < 8; ++j) pk[j] = tile[c * 8 + j][e];
        *(u16x8*)(dst + (size_t)e * SS + c * 8) = pk;
    }
}

// ---------------------------------------------------------------------------
// Causal flash attention v10 — BARRIER-FREE main loop.
// K is loaded directly global->registers per wave (K tiles are L2-hot, 8KB;
// 4x redundant reads cost ~L2 bandwidth, far from its ceiling) instead of
// LDS staging. This removes BOTH __syncthreads from the loop: the 16 waves
// resident per CU become fully independent, so each wave's L2/serial-chain
// stalls are hidden by the others (R5-R9 were stuck at 123us because the
// block barrier lockstepped the QK->softmax->PV chain).
// LDS = epilogue transpose buffer only (18KB). VGPR ~100 (<=128, 4 blk/CU).
// Swapped-operand QK^T, lane-local softmax, permlane-swap P^T crossbar,
// max3 trees + tree sum, defer-max THR=8. Q pre-scaled by 0.125*log2e.
// Grid: 64 bh * 16 qb (longest-first, R8 mapping — R9 remap raised FETCH 3x
// with zero gain and was reverted). Block: 256 thr, 4 waves.
// ---------------------------------------------------------------------------
__global__ __launch_bounds__(256, 4) void attn_fwd(
    const unsigned short* __restrict__ Q, const unsigned short* __restrict__ K,
    const unsigned short* __restrict__ VT, unsigned short* __restrict__ O) {
    int bid = blockIdx.x;
    int qb = 15 - (bid >> 6);          // heaviest q-blocks first
    int bh = bid & 63;
    int b = bh >> 4, h = bh & 15;
    int tid = threadIdx.x, lane = tid & 63, w = tid >> 6;
    int g = lane >> 4, lr = lane & 15;

    __shared__ unsigned short smem[128 * 72];   // epilogue transpose only

    const int q0 = qb * 128;
    const unsigned short* Qp = Q + ((size_t)bh * SS + q0 + w * 32) * HDD;
    const unsigned short* Kp = K + (size_t)bh * SS * HDD;
    const unsigned short* Vp = VT + (size_t)bh * HDD * SS;

    // Q B-fragments: lane holds Q[q = qg*16+lr][d = kk*32 + g*8 + i]
    bf16x8 qf[2][2];
#pragma unroll
    for (int qg = 0; qg < 2; ++qg) {
        qf[qg][0] = *(const bf16x8*)(Qp + (qg * 16 + lr) * 64 + g * 8);
        qf[qg][1] = *(const bf16x8*)(Qp + (qg * 16 + lr) * 64 + 32 + g * 8);
    }

    float m_[2] = {-3.0e38f, -3.0e38f};
    float l_[2] = {0.f, 0.f};
    f32x4 acc[2][4] = {};   // acc[qg][ct2]: O^T[e = ct2*16+g*4+r][q = lr]

    const int nt = 2 * qb + 2;

    for (int it = 0; it < nt; ++it) {
        int t0 = it * 64;

        // K fragments direct global->reg: kf[kk][ct] = K[t0+ct*16+lr][kk*32+g*8..]
        bf16x8 kf[2][4];
#pragma unroll
        for (int kk = 0; kk < 2; ++kk)
#pragma unroll
            for (int ct = 0; ct < 4; ++ct)
                kf[kk][ct] = *(const bf16x8*)(Kp + (size_t)(t0 + ct * 16 + lr) * HDD + kk * 32 + g * 8);

        // S^T = mfma(K, Q): sacc[qg][ct] lane: q=lr, key = t0 + ct*16 + g*4 + r
        f32x4 sacc[2][4] = {};
        __builtin_amdgcn_s_setprio(1);
#pragma unroll
        for (int kk = 0; kk < 2; ++kk)
#pragma unroll
            for (int ct = 0; ct < 4; ++ct)
#pragma unroll
                for (int qg = 0; qg < 2; ++qg)
                    sacc[qg][ct] = __builtin_amdgcn_mfma_f32_16x16x32_bf16(kf[kk][ct], qf[qg][kk], sacc[qg][ct], 0, 0, 0);
        __builtin_amdgcn_s_setprio(0);

        // causal mask (last two tiles)
        if (it >= nt - 2) {
#pragma unroll
            for (int qg = 0; qg < 2; ++qg) {
                int kmax = q0 + w * 32 + qg * 16 + lr - t0;  // keys <= kmax allowed
#pragma unroll
                for (int ct = 0; ct < 4; ++ct)
#pragma unroll
                    for (int r = 0; r < 4; ++r)
                        if (ct * 16 + g * 4 + r > kmax) sacc[qg][ct][r] = -3.0e38f;
            }
        }

        // per-lane online softmax (exp2 domain), defer-max THR=8
        bf16x8 pvf[2][2];
#pragma unroll
        for (int qg = 0; qg < 2; ++qg) {
            // max via v_max3 tree (16 values -> 8 ops)
            float t = fmax3(
                fmax3(fmax3(sacc[qg][0][0], sacc[qg][0][1], sacc[qg][0][2]),
                      fmax3(sacc[qg][0][3], sacc[qg][1][0], sacc[qg][1][1]),
                      fmax3(sacc[qg][1][2], sacc[qg][1][3], sacc[qg][2][0])),
                fmax3(sacc[qg][2][1], sacc[qg][2][2], sacc[qg][2][3]),
                fmax3(sacc[qg][3][0], sacc[qg][3][1],
                      fmaxf(sacc[qg][3][2], sacc[qg][3][3])));
            t = fmaxf(t, __shfl_xor(t, 16));
            t = fmaxf(t, __shfl_xor(t, 32));
            bool need = t > m_[qg] + 8.0f;
            if (__any((int)need)) {
                float nm = fmaxf(m_[qg], t);
                float sf = exp2f(m_[qg] - nm);
                m_[qg] = nm;
                l_[qg] *= sf;
#pragma unroll
                for (int ct = 0; ct < 4; ++ct)
#pragma unroll
                    for (int r = 0; r < 4; ++r) acc[qg][ct][r] *= sf;
            }
            // exp2 + 4-way tree sum (short dep chains)
            float rs0 = 0.f, rs1 = 0.f, rs2 = 0.f, rs3 = 0.f;
#pragma unroll
            for (int ct = 0; ct < 4; ++ct) {
                float p0 = exp2f(sacc[qg][ct][0] - m_[qg]);
                float p1 = exp2f(sacc[qg][ct][1] - m_[qg]);
                float p2 = exp2f(sacc[qg][ct][2] - m_[qg]);
                float p3 = exp2f(sacc[qg][ct][3] - m_[qg]);
                sacc[qg][ct][0] = p0; sacc[qg][ct][1] = p1;
                sacc[qg][ct][2] = p2; sacc[qg][ct][3] = p3;
                rs0 += p0; rs1 += p1; rs2 += p2; rs3 += p3;
            }
            float rs = (rs0 + rs1) + (rs2 + rs3);
            rs += __shfl_xor(rs, 16);
            rs += __shfl_xor(rs, 32);
            l_[qg] += rs;

            // pack P^T to bf16 pairs: pk[ct][c] = keys (ct*16+g*4+2c, +1)
            unsigned int pk[4][2];
#pragma unroll
            for (int ct = 0; ct < 4; ++ct) {
                pk[ct][0] = cvt_pk_bf16(sacc[qg][ct][0], sacc[qg][ct][1]);
                pk[ct][1] = cvt_pk_bf16(sacc[qg][ct][2], sacc[qg][ct][3]);
            }
            // permlane crossbar: (reg k4 <-> lane b5), then (reg k3 <-> lane b4)
            unsigned int out[2][4];
#pragma unroll
            for (int s5 = 0; s5 < 2; ++s5)
#pragma unroll
                for (int s1 = 0; s1 < 2; ++s1) {
                    unsigned int a = pk[2 * s5][s1];
                    unsigned int bq = pk[2 * s5 + 1][s1];
                    asm("v_permlane32_swap_b32 %0, %1" : "+v"(a), "+v"(bq));
                    asm("v_permlane16_swap_b32 %0, %1" : "+v"(a), "+v"(bq));
                    out[s5][s1] = a;        // j = s1   (k2=0)
                    out[s5][2 + s1] = bq;   // j = 2+s1 (k2=1)
                }
#pragma unroll
            for (int kk2 = 0; kk2 < 2; ++kk2) {
                u32x4 tmp;
                tmp[0] = out[kk2][0]; tmp[1] = out[kk2][1];
                tmp[2] = out[kk2][2]; tmp[3] = out[kk2][3];
                pvf[qg][kk2] = __builtin_bit_cast(bf16x8, tmp);
            }
        }

        // O^T += V^T P^T : A = VT rows (direct global, at use-site), B = pvf
#pragma unroll
        for (int kk2 = 0; kk2 < 2; ++kk2)
#pragma unroll
            for (int ct2 = 0; ct2 < 4; ++ct2) {
                bf16x8 vf = *(const bf16x8*)(Vp + (size_t)(ct2 * 16 + lr) * SS + t0 + kk2 * 32 + g * 8);
                __builtin_amdgcn_s_setprio(1);
#pragma unroll
                for (int qg = 0; qg < 2; ++qg)
                    acc[qg][ct2] = __builtin_amdgcn_mfma_f32_16x16x32_bf16(vf, pvf[qg][kk2], acc[qg][ct2], 0, 0, 0);
                __builtin_amdgcn_s_setprio(0);
            }
        // no __syncthreads: waves are fully independent in the main loop
    }

    // epilogue: normalize, transpose via LDS, coalesced store [B,S,D]
#pragma unroll
    for (int qg = 0; qg < 2; ++qg) {
        float invl = 1.0f / l_[qg];
#pragma unroll
        for (int ct2 = 0; ct2 < 4; ++ct2)
#pragma unroll
            for (int r = 0; r < 4; ++r)
                smem[(w * 32 + qg * 16 + lr) * 72 + ct2 * 16 + g * 4 + r] =
                    f32_to_bf16(acc[qg][ct2][r] * invl);
    }
    __syncthreads();
#pragma unroll
    for (int itr = 0; itr < 4; ++itr) {
        int idx = itr * 256 + tid;
        int row = idx >> 3, seg = idx & 7;
        u16x8 vv = *(const u16x8*)&smem[row * 72 + seg * 8];
        *(u16x8*)(O + ((size_t)(b * SS + q0 + row)) * DD + h * 64 + seg * 8) = vv;
    }
}

// ---------------------------------------------------------------------------
extern "C" void kernel_launch(void* const* d_in, const int* in_sizes, int n_in,
                              void* d_out, int out_size, void* d_ws, size_t ws_size,
                              hipStream_t stream) {
    (void)in_sizes; (void)n_in; (void)out_size; (void)ws_size;
    const float* x  = (const float*)d_in[0];
    const float* Wq = (const float*)d_in[1];
    const float* Wk = (const float*)d_in[2];
    const float* Wv = (const float*)d_in[3];
    const float* WO = (const float*)d_in[4];
    float* out = (float*)d_out;

    char* ws = (char*)d_ws;
    unsigned short* xb    = (unsigned short*)(ws + 0);          // 16 MB
    unsigned short* wqkvT = (unsigned short*)(ws + 16777216);   // 6 MB
    unsigned short* wob   = (unsigned short*)(ws + 23068672);   // 2 MB
    unsigned short* Qb    = (unsigned short*)(ws + 25165824);   // 16 MB
    unsigned short* Kb    = (unsigned short*)(ws + 41943040);   // 16 MB
    unsigned short* Vb    = (unsigned short*)(ws + 58720256);   // 16 MB
    unsigned short* VTb   = (unsigned short*)(ws + 75497472);   // 16 MB
    unsigned short* Ob    = (unsigned short*)(ws + 92274688);   // 16 MB

    convert_f32_bf16<<<2048, 256, 0, stream>>>(x, xb, (BB * SS * DD) / 4);
    convert_f32_bf16<<<1024, 256, 0, stream>>>(WO, wob, (DD * DD) / 4);
    pack_wqkv<<<768, 256, 0, stream>>>(Wq, Wk, Wv, wqkvT);
    gemm128<0><<<64 * 24, 256, 0, stream>>>(xb, wqkvT, (void*)Qb, (void*)Kb, (void*)Vb, 24);
    transpose_v<<<2048, 256, 0, stream>>>(Vb, VTb);
    attn_fwd<<<1024, 256, 0, stream>>>(Qb, Kb, VTb, Ob);
    gemm128<1><<<64 * 8, 256, 0, stream>>>(Ob, wob, (void*)out, nullptr, nullptr, 8);
}

// Round 11
// 177.718 us; speedup vs baseline: 1.4963x; 1.4963x over previous
//
#include <hip/hip_runtime.h>
#include <hip/hip_bf16.h>

// Problem constants
#define BB 4
#define SS 2048
#define DD 1024
#define HH 16
#define HDD 64

typedef __attribute__((ext_vector_type(8))) short bf16x8;
typedef __attribute__((ext_vector_type(8))) unsigned short u16x8;
typedef __attribute__((ext_vector_type(4))) float f32x4;
typedef __attribute__((ext_vector_type(4))) unsigned int u32x4;

#define GLD_LDS16(g, l) \
    __builtin_amdgcn_global_load_lds((const __attribute__((address_space(1))) void*)(g), \
                                     (__attribute__((address_space(3))) void*)(l), 16, 0, 0)

__device__ __forceinline__ unsigned short f32_to_bf16(float f) {
    unsigned int u = __float_as_uint(f);
    u += 0x7fffu + ((u >> 16) & 1u);   // RTNE
    return (unsigned short)(u >> 16);
}

__device__ __forceinline__ unsigned int cvt_pk_bf16(float lo, float hi) {
    unsigned int r;
    asm("v_cvt_pk_bf16_f32 %0, %1, %2" : "=v"(r) : "v"(lo), "v"(hi));
    return r;
}

__device__ __forceinline__ float fmax3(float a, float b, float c) {
    return fmaxf(fmaxf(a, b), c);   // fuses to v_max3_f32
}

// ---------------------------------------------------------------------------
// fp32 -> bf16 convert (vectorized, grid-stride)
// ---------------------------------------------------------------------------
__global__ __launch_bounds__(256) void convert_f32_bf16(
    const float* __restrict__ in, unsigned short* __restrict__ out, int n4) {
    int stride = gridDim.x * blockDim.x;
    for (int i = blockIdx.x * blockDim.x + threadIdx.x; i < n4; i += stride) {
        float4 v = ((const float4*)in)[i];
        ushort4 o;
        o.x = f32_to_bf16(v.x); o.y = f32_to_bf16(v.y);
        o.z = f32_to_bf16(v.z); o.w = f32_to_bf16(v.w);
        ((ushort4*)out)[i] = o;
    }
}

// ---------------------------------------------------------------------------
// Pack Wq/Wk/Wv [H][D][HD] fp32 -> WT [3*D][D] bf16 (B^T layout)
// ---------------------------------------------------------------------------
__global__ __launch_bounds__(256) void pack_wqkv(
    const float* __restrict__ Wq, const float* __restrict__ Wk,
    const float* __restrict__ Wv, unsigned short* __restrict__ WT) {
    int bid = blockIdx.x;
    int w = bid >> 8, h = (bid >> 4) & 15, db = bid & 15;
    const float* src = (w == 0) ? Wq : ((w == 1) ? Wk : Wv);
    __shared__ float tile[64][68];
    int t = threadIdx.x;
    for (int p = t; p < 1024; p += 256) {
        int row = p >> 4, c4 = p & 15;
        float4 v = *(const float4*)(src + ((size_t)(h * 1024 + db * 64 + row)) * 64 + c4 * 4);
        tile[row][c4 * 4 + 0] = v.x; tile[row][c4 * 4 + 1] = v.y;
        tile[row][c4 * 4 + 2] = v.z; tile[row][c4 * 4 + 3] = v.w;
    }
    __syncthreads();
    size_t wbase = (size_t)w * 1024 * 1024;
    for (int p = t; p < 512; p += 256) {
        int e = p >> 3, c = p & 7;
        u16x8 pk;
#pragma unroll
        for (int j = 0; j < 8; ++j) pk[j] = f32_to_bf16(tile[c * 8 + j][e]);
        *(u16x8*)(WT + wbase + (size_t)(h * 64 + e) * 1024 + db * 64 + c * 8) = pk;
    }
}

// ---------------------------------------------------------------------------
// 128x128 tile bf16 GEMM, BK=64, 4 waves, global_load_lds + XOR-swizzled LDS.
// XCD-aware bijective block swizzle (requires gridDim.x % 8 == 0). setprio
// around MFMA cluster. EPI 0: scatter C (bf16) into Q/K/V [B,H,S,HD]; Q
// pre-scaled by 0.125*log2e. EPI 1: C fp32 [M][1024].
// ---------------------------------------------------------------------------
template <int EPI>
__global__ __launch_bounds__(256) void gemm128(
    const unsigned short* __restrict__ A, const unsigned short* __restrict__ Bm,
    void* __restrict__ C0, void* __restrict__ C1, void* __restrict__ C2, int NBt) {
    __shared__ unsigned short As[128 * 64];
    __shared__ unsigned short Bs[128 * 64];
    // XCD swizzle: XCD x (bid%8) gets a contiguous chunk of tile space
    int cpx = gridDim.x >> 3;
    int bid = (blockIdx.x & 7) * cpx + (blockIdx.x >> 3);
    int mb = bid / NBt, nb = bid % NBt;
    int tid = threadIdx.x;
    int lane = tid & 63, wid = tid >> 6;
    int wm = wid >> 1, wn = wid & 1;
    int g = lane >> 4, lr = lane & 15;
    int srow = lane >> 3, sch = lane & 7;
    int scol = (sch ^ srow) * 8;
    const int M0 = mb * 128, N0 = nb * 128;

    f32x4 acc[4][4] = {};

    for (int kt = 0; kt < 16; ++kt) {
        __syncthreads();
#pragma unroll
        for (int i = 0; i < 4; ++i) {
            int c = wid * 4 + i;
            int row = c * 8 + srow;
            GLD_LDS16(A + (size_t)(M0 + row) * 1024 + kt * 64 + scol, As + c * 512);
            GLD_LDS16(Bm + (size_t)(N0 + row) * 1024 + kt * 64 + scol, Bs + c * 512);
        }
        __syncthreads();
#pragma unroll
        for (int kk = 0; kk < 2; ++kk) {
            bf16x8 af[4], bfr[4];
#pragma unroll
            for (int i = 0; i < 4; ++i) {
                int row = wm * 64 + i * 16 + lr;
                int ch = (kk * 4 + g) ^ (row & 7);
                af[i] = *(const bf16x8*)(As + row * 64 + ch * 8);
                int rowb = wn * 64 + i * 16 + lr;
                int chb = (kk * 4 + g) ^ (rowb & 7);
                bfr[i] = *(const bf16x8*)(Bs + rowb * 64 + chb * 8);
            }
            __builtin_amdgcn_s_setprio(1);
#pragma unroll
            for (int i = 0; i < 4; ++i)
#pragma unroll
                for (int j = 0; j < 4; ++j)
                    acc[i][j] = __builtin_amdgcn_mfma_f32_16x16x32_bf16(af[i], bfr[j], acc[i][j], 0, 0, 0);
            __builtin_amdgcn_s_setprio(0);
        }
    }

    if constexpr (EPI == 0) {
        unsigned short* Qo = (unsigned short*)C0;
        unsigned short* Ko = (unsigned short*)C1;
        unsigned short* Vo = (unsigned short*)C2;
        const float QSCALE = 0.125f * 1.4426950408889634f;  // scale * log2(e)
#pragma unroll
        for (int i = 0; i < 4; ++i)
#pragma unroll
            for (int j = 0; j < 4; ++j)
#pragma unroll
                for (int r = 0; r < 4; ++r) {
                    int m = M0 + wm * 64 + i * 16 + g * 4 + r;
                    int n = N0 + wn * 64 + j * 16 + lr;
                    int b = m >> 11, s = m & 2047;
                    int w = n >> 10, h = (n >> 6) & 15, e = n & 63;
                    unsigned short* dst = (w == 0) ? Qo : ((w == 1) ? Ko : Vo);
                    float scl = (w == 0) ? QSCALE : 1.0f;
                    dst[((size_t)(b * HH + h) * SS + s) * HDD + e] = f32_to_bf16(acc[i][j][r] * scl);
                }
    } else {
        float* Co = (float*)C0;
#pragma unroll
        for (int i = 0; i < 4; ++i)
#pragma unroll
            for (int j = 0; j < 4; ++j)
#pragma unroll
                for (int r = 0; r < 4; ++r) {
                    int m = M0 + wm * 64 + i * 16 + g * 4 + r;
                    int n = N0 + wn * 64 + j * 16 + lr;
                    Co[(size_t)m * 1024 + n] = acc[i][j][r];
                }
    }
}

// ---------------------------------------------------------------------------
// V [B,H,S,HD] -> VT [B,H,HD,S]  (LDS tile transpose)
// ---------------------------------------------------------------------------
__global__ __launch_bounds__(256) void transpose_v(
    const unsigned short* __restrict__ V, unsigned short* __restrict__ VT) {
    int bh = blockIdx.x >> 5, sb = blockIdx.x & 31;
    __shared__ unsigned short tile[64][72];
    const unsigned short* src = V + ((size_t)bh * SS + sb * 64) * HDD;
    int t = threadIdx.x;
    for (int p = t; p < 512; p += 256) {
        int row = p >> 3, c = p & 7;
        *(u16x8*)&tile[row][c * 8] = *(const u16x8*)(src + row * 64 + c * 8);
    }
    __syncthreads();
    unsigned short* dst = VT + (size_t)bh * HDD * SS + sb * 64;
    for (int p = t; p < 512; p += 256) {
        int e = p >> 3, c = p & 7;
        u16x8 pk;
#pragma unroll
        for (int j = 0; j < 8; ++j) pk[j] = tile[c * 8 + j][e];
        *(u16x8*)(dst + (size_t)e * SS + c * 8) = pk;
    }
}

// ---------------------------------------------------------------------------
// Causal flash attention v11 — v8 structure + V^T ALSO staged to LDS.
// R10 lesson: the LDS dbuf+barrier IS the prefetch engine (K direct->reg
// lost it: MfmaUtil 12->8.6). R6 lesson: V prefetch into registers gets
// rematerialized at VGPR=64 (FETCH +17MB). Fix: V^T tiles staged via
// global_load_lds (costs 0 VGPRs, per-lane scattered source, linear LDS
// dest, same XOR swizzle as K), double-buffered with K, consumed by PV as
// ds_read_b128 -> no L2 latency inside the PV MFMA chain, 4x less V fetch.
// LDS 32KB loop (K 2x8KB + V 2x8KB), epilogue transpose unioned.
// Swapped-operand QK^T, lane-local softmax, permlane-swap P^T crossbar,
// max3 trees + tree sum, defer-max THR=8. Q pre-scaled by 0.125*log2e.
// Grid: 64 bh * 16 qb (longest-first). Block: 256 thr, 4 waves. (256,4).
// ---------------------------------------------------------------------------
__global__ __launch_bounds__(256, 4) void attn_fwd(
    const unsigned short* __restrict__ Q, const unsigned short* __restrict__ K,
    const unsigned short* __restrict__ VT, unsigned short* __restrict__ O) {
    int bid = blockIdx.x;
    int qb = 15 - (bid >> 6);          // heaviest q-blocks first
    int bh = bid & 63;
    int b = bh >> 4, h = bh & 15;
    int tid = threadIdx.x, lane = tid & 63, w = tid >> 6;
    int g = lane >> 4, lr = lane & 15;
    int srow = lane >> 3, sch = lane & 7;
    int scol = (sch ^ srow) * 8;       // pre-swizzled global chunk offset

    // 32KB loop LDS: [0..4095] K buf0, [4096..8191] K buf1,
    //                [8192..12287] V buf0, [12288..16383] V buf1 (shorts)
    // epilogue transpose (128*72 shorts = 18KB) aliases the front.
    __shared__ unsigned short smem[16384];

    const int q0 = qb * 128;
    const unsigned short* Qp = Q + ((size_t)bh * SS + q0 + w * 32) * HDD;
    const unsigned short* Kp = K + (size_t)bh * SS * HDD;
    const unsigned short* Vp = VT + (size_t)bh * HDD * SS;

    // Q B-fragments: lane holds Q[q = qg*16+lr][d = kk*32 + g*8 + i]
    bf16x8 qf[2][2];
#pragma unroll
    for (int qg = 0; qg < 2; ++qg) {
        qf[qg][0] = *(const bf16x8*)(Qp + (qg * 16 + lr) * 64 + g * 8);
        qf[qg][1] = *(const bf16x8*)(Qp + (qg * 16 + lr) * 64 + 32 + g * 8);
    }

    float m_[2] = {-3.0e38f, -3.0e38f};
    float l_[2] = {0.f, 0.f};
    f32x4 acc[2][4] = {};   // acc[qg][ct2]: O^T[e = ct2*16+g*4+r][q = lr]

    const int nt = 2 * qb + 2;

    // prologue: stage K,V tile 0 into buffer 0
#pragma unroll
    for (int i = 0; i < 2; ++i) {
        int c = w * 2 + i;
        int row = c * 8 + srow;
        GLD_LDS16(Kp + (size_t)row * HDD + scol, smem + c * 512);
        GLD_LDS16(Vp + (size_t)row * SS + scol, smem + 8192 + c * 512);
    }
    __syncthreads();

    for (int it = 0; it < nt; ++it) {
        unsigned short* Kcur = smem + (it & 1) * 4096;
        unsigned short* Vcur = smem + 8192 + (it & 1) * 4096;
        if (it + 1 < nt) {
            int t1 = (it + 1) * 64;
            unsigned short* Knxt = smem + ((it & 1) ^ 1) * 4096;
            unsigned short* Vnxt = smem + 8192 + ((it & 1) ^ 1) * 4096;
#pragma unroll
            for (int i = 0; i < 2; ++i) {
                int c = w * 2 + i;
                int row = c * 8 + srow;
                GLD_LDS16(Kp + (size_t)(t1 + row) * HDD + scol, Knxt + c * 512);
                GLD_LDS16(Vp + (size_t)row * SS + t1 + scol, Vnxt + c * 512);
            }
        }
        int t0 = it * 64;

        // S^T = mfma(K, Q): sacc[qg][ct] lane: q=lr, key = t0 + ct*16 + g*4 + r
        f32x4 sacc[2][4] = {};
        __builtin_amdgcn_s_setprio(1);
#pragma unroll
        for (int kk = 0; kk < 2; ++kk)
#pragma unroll
            for (int ct = 0; ct < 4; ++ct) {
                int row = ct * 16 + lr;
                int ch = (kk * 4 + g) ^ (row & 7);
                bf16x8 kf = *(const bf16x8*)(Kcur + row * 64 + ch * 8);
#pragma unroll
                for (int qg = 0; qg < 2; ++qg)
                    sacc[qg][ct] = __builtin_amdgcn_mfma_f32_16x16x32_bf16(kf, qf[qg][kk], sacc[qg][ct], 0, 0, 0);
            }
        __builtin_amdgcn_s_setprio(0);

        // causal mask (last two tiles)
        if (it >= nt - 2) {
#pragma unroll
            for (int qg = 0; qg < 2; ++qg) {
                int kmax = q0 + w * 32 + qg * 16 + lr - t0;  // keys <= kmax allowed
#pragma unroll
                for (int ct = 0; ct < 4; ++ct)
#pragma unroll
                    for (int r = 0; r < 4; ++r)
                        if (ct * 16 + g * 4 + r > kmax) sacc[qg][ct][r] = -3.0e38f;
            }
        }

        // per-lane online softmax (exp2 domain), defer-max THR=8
        bf16x8 pvf[2][2];
#pragma unroll
        for (int qg = 0; qg < 2; ++qg) {
            // max via v_max3 tree (16 values -> 8 ops)
            float t = fmax3(
                fmax3(fmax3(sacc[qg][0][0], sacc[qg][0][1], sacc[qg][0][2]),
                      fmax3(sacc[qg][0][3], sacc[qg][1][0], sacc[qg][1][1]),
                      fmax3(sacc[qg][1][2], sacc[qg][1][3], sacc[qg][2][0])),
                fmax3(sacc[qg][2][1], sacc[qg][2][2], sacc[qg][2][3]),
                fmax3(sacc[qg][3][0], sacc[qg][3][1],
                      fmaxf(sacc[qg][3][2], sacc[qg][3][3])));
            t = fmaxf(t, __shfl_xor(t, 16));
            t = fmaxf(t, __shfl_xor(t, 32));
            bool need = t > m_[qg] + 8.0f;
            if (__any((int)need)) {
                float nm = fmaxf(m_[qg], t);
                float sf = exp2f(m_[qg] - nm);
                m_[qg] = nm;
                l_[qg] *= sf;
#pragma unroll
                for (int ct = 0; ct < 4; ++ct)
#pragma unroll
                    for (int r = 0; r < 4; ++r) acc[qg][ct][r] *= sf;
            }
            // exp2 + 4-way tree sum (short dep chains)
            float rs0 = 0.f, rs1 = 0.f, rs2 = 0.f, rs3 = 0.f;
#pragma unroll
            for (int ct = 0; ct < 4; ++ct) {
                float p0 = exp2f(sacc[qg][ct][0] - m_[qg]);
                float p1 = exp2f(sacc[qg][ct][1] - m_[qg]);
                float p2 = exp2f(sacc[qg][ct][2] - m_[qg]);
                float p3 = exp2f(sacc[qg][ct][3] - m_[qg]);
                sacc[qg][ct][0] = p0; sacc[qg][ct][1] = p1;
                sacc[qg][ct][2] = p2; sacc[qg][ct][3] = p3;
                rs0 += p0; rs1 += p1; rs2 += p2; rs3 += p3;
            }
            float rs = (rs0 + rs1) + (rs2 + rs3);
            rs += __shfl_xor(rs, 16);
            rs += __shfl_xor(rs, 32);
            l_[qg] += rs;

            // pack P^T to bf16 pairs: pk[ct][c] = keys (ct*16+g*4+2c, +1)
            unsigned int pk[4][2];
#pragma unroll
            for (int ct = 0; ct < 4; ++ct) {
                pk[ct][0] = cvt_pk_bf16(sacc[qg][ct][0], sacc[qg][ct][1]);
                pk[ct][1] = cvt_pk_bf16(sacc[qg][ct][2], sacc[qg][ct][3]);
            }
            // permlane crossbar: (reg k4 <-> lane b5), then (reg k3 <-> lane b4)
            unsigned int out[2][4];
#pragma unroll
            for (int s5 = 0; s5 < 2; ++s5)
#pragma unroll
                for (int s1 = 0; s1 < 2; ++s1) {
                    unsigned int a = pk[2 * s5][s1];
                    unsigned int bq = pk[2 * s5 + 1][s1];
                    asm("v_permlane32_swap_b32 %0, %1" : "+v"(a), "+v"(bq));
                    asm("v_permlane16_swap_b32 %0, %1" : "+v"(a), "+v"(bq));
                    out[s5][s1] = a;        // j = s1   (k2=0)
                    out[s5][2 + s1] = bq;   // j = 2+s1 (k2=1)
                }
#pragma unroll
            for (int kk2 = 0; kk2 < 2; ++kk2) {
                u32x4 tmp;
                tmp[0] = out[kk2][0]; tmp[1] = out[kk2][1];
                tmp[2] = out[kk2][2]; tmp[3] = out[kk2][3];
                pvf[qg][kk2] = __builtin_bit_cast(bf16x8, tmp);
            }
        }

        // O^T += V^T P^T : A = V^T rows from LDS (swizzled ds_read), B = pvf
#pragma unroll
        for (int kk2 = 0; kk2 < 2; ++kk2)
#pragma unroll
            for (int ct2 = 0; ct2 < 4; ++ct2) {
                int row = ct2 * 16 + lr;
                int ch = (kk2 * 4 + g) ^ (row & 7);
                bf16x8 vf = *(const bf16x8*)(Vcur + row * 64 + ch * 8);
                __builtin_amdgcn_s_setprio(1);
#pragma unroll
                for (int qg = 0; qg < 2; ++qg)
                    acc[qg][ct2] = __builtin_amdgcn_mfma_f32_16x16x32_bf16(vf, pvf[qg][kk2], acc[qg][ct2], 0, 0, 0);
                __builtin_amdgcn_s_setprio(0);
            }

        __syncthreads();  // next K,V staged; all waves done with cur buffers
    }

    // epilogue: normalize, transpose via LDS (aliases loop buffers), store
#pragma unroll
    for (int qg = 0; qg < 2; ++qg) {
        float invl = 1.0f / l_[qg];
#pragma unroll
        for (int ct2 = 0; ct2 < 4; ++ct2)
#pragma unroll
            for (int r = 0; r < 4; ++r)
                smem[(w * 32 + qg * 16 + lr) * 72 + ct2 * 16 + g * 4 + r] =
                    f32_to_bf16(acc[qg][ct2][r] * invl);
    }
    __syncthreads();
#pragma unroll
    for (int itr = 0; itr < 4; ++itr) {
        int idx = itr * 256 + tid;
        int row = idx >> 3, seg = idx & 7;
        u16x8 vv = *(const u16x8*)&smem[row * 72 + seg * 8];
        *(u16x8*)(O + ((size_t)(b * SS + q0 + row)) * DD + h * 64 + seg * 8) = vv;
    }
}

// ---------------------------------------------------------------------------
extern "C" void kernel_launch(void* const* d_in, const int* in_sizes, int n_in,
                              void* d_out, int out_size, void* d_ws, size_t ws_size,
                              hipStream_t stream) {
    (void)in_sizes; (void)n_in; (void)out_size; (void)ws_size;
    const float* x  = (const float*)d_in[0];
    const float* Wq = (const float*)d_in[1];
    const float* Wk = (const float*)d_in[2];
    const float* Wv = (const float*)d_in[3];
    const float* WO = (const float*)d_in[4];
    float* out = (float*)d_out;

    char* ws = (char*)d_ws;
    unsigned short* xb    = (unsigned short*)(ws + 0);          // 16 MB
    unsigned short* wqkvT = (unsigned short*)(ws + 16777216);   // 6 MB
    unsigned short* wob   = (unsigned short*)(ws + 23068672);   // 2 MB
    unsigned short* Qb    = (unsigned short*)(ws + 25165824);   // 16 MB
    unsigned short* Kb    = (unsigned short*)(ws + 41943040);   // 16 MB
    unsigned short* Vb    = (unsigned short*)(ws + 58720256);   // 16 MB
    unsigned short* VTb   = (unsigned short*)(ws + 75497472);   // 16 MB
    unsigned short* Ob    = (unsigned short*)(ws + 92274688);   // 16 MB

    convert_f32_bf16<<<2048, 256, 0, stream>>>(x, xb, (BB * SS * DD) / 4);
    convert_f32_bf16<<<1024, 256, 0, stream>>>(WO, wob, (DD * DD) / 4);
    pack_wqkv<<<768, 256, 0, stream>>>(Wq, Wk, Wv, wqkvT);
    gemm128<0><<<64 * 24, 256, 0, stream>>>(xb, wqkvT, (void*)Qb, (void*)Kb, (void*)Vb, 24);
    transpose_v<<<2048, 256, 0, stream>>>(Vb, VTb);
    attn_fwd<<<1024, 256, 0, stream>>>(Qb, Kb, VTb, Ob);
    gemm128<1><<<64 * 8, 256, 0, stream>>>(Ob, wob, (void*)out, nullptr, nullptr, 8);
}